// Round 5
// baseline (489.197 us; speedup 1.0000x reference)
//
#include <hip/hip_runtime.h>

typedef unsigned short u16;
typedef float f32x4 __attribute__((ext_vector_type(4)));
typedef __bf16 bf16x8 __attribute__((ext_vector_type(8)));

#define DEV static __device__ __forceinline__

constexpr int BB = 2, TT = 2048, DD = 2048, HH = 16;

DEV u16 to_bf16u(float f) { return __builtin_bit_cast(u16, (__bf16)f); }

DEV void gl_lds16(const void* g, void* l) {
  __builtin_amdgcn_global_load_lds((const __attribute__((address_space(1))) void*)g,
                                   (__attribute__((address_space(3))) void*)l, 16, 0, 0);
}

DEV f32x4 mfma16(bf16x8 a, bf16x8 b, f32x4 c) {
  return __builtin_amdgcn_mfma_f32_16x16x32_bf16(a, b, c, 0, 0, 0);
}

DEV void bar() { asm volatile("s_barrier" ::: "memory"); }

// ---------------- fp32 -> bf16 convert (8 elems/thread) ----------------
__global__ __launch_bounds__(256) void k_cvt(const float* __restrict__ in,
                                             u16* __restrict__ out, int n) {
  int i = (blockIdx.x * 256 + threadIdx.x) * 8;
  if (i >= n) return;
  float4 a = *(const float4*)(in + i);
  float4 b = *(const float4*)(in + i + 4);
  ushort4 u0, u1;
  u0.x = to_bf16u(a.x); u0.y = to_bf16u(a.y); u0.z = to_bf16u(a.z); u0.w = to_bf16u(a.w);
  u1.x = to_bf16u(b.x); u1.y = to_bf16u(b.y); u1.z = to_bf16u(b.z); u1.w = to_bf16u(b.w);
  *(ushort4*)(out + i) = u0;
  *(ushort4*)(out + i + 4) = u1;
}

// ---------------- weight transpose + convert: w (K,N) -> wt (N,K) bf16 ----------------
__global__ __launch_bounds__(256) void k_wtrans(const float* __restrict__ w0, const float* __restrict__ w1,
                                                const float* __restrict__ w2, const float* __restrict__ w3,
                                                u16* __restrict__ o0, u16* __restrict__ o1,
                                                u16* __restrict__ o2, u16* __restrict__ o3) {
  __shared__ float tile[32][33];
  const float* w; u16* o;
  switch (blockIdx.z) {
    case 0: w = w0; o = o0; break;
    case 1: w = w1; o = o1; break;
    case 2: w = w2; o = o2; break;
    default: w = w3; o = o3; break;
  }
  int bx = blockIdx.x * 32;  // n
  int by = blockIdx.y * 32;  // k
  int tx = threadIdx.x & 31, ty = threadIdx.x >> 5;
#pragma unroll
  for (int j = ty; j < 32; j += 8)
    tile[j][tx] = w[(size_t)(by + j) * DD + bx + tx];
  __syncthreads();
#pragma unroll
  for (int j = ty; j < 32; j += 8)
    o[(size_t)(bx + j) * DD + by + tx] = to_bf16u(tile[tx][j]);
}

// ---------------- 256^2 8-phase GEMM (m201 template, plain HIP) ----------------
// C(4096,2048) = A(4096,2048) * Bt(2048,2048)^T + bias
// OUTMODE 0: QKV fused (blockIdx.z = sel; sel2 writes V transposed (B,H,128,T))
// OUTMODE 1: f32 out (O-projection)
// 512 threads = 8 waves (2 wm x 4 wn); wave tile 128x64; BK=64; LDS 128 KiB dbuf.
template <int OUTMODE>
__global__ __launch_bounds__(512, 2) void k_gemm256(
    const u16* __restrict__ A,
    const u16* __restrict__ W0, const u16* __restrict__ W1, const u16* __restrict__ W2,
    const float* __restrict__ b0, const float* __restrict__ b1, const float* __restrict__ b2,
    u16* __restrict__ O0, u16* __restrict__ O1, u16* __restrict__ O2,
    float* __restrict__ OF) {
  extern __shared__ char lds[];
  constexpr int K = 2048, NK = K / 64;  // 32 K-tiles
  const int t = threadIdx.x;
  const int lane = t & 63, lg = lane >> 4, lr = lane & 15;
  const int wid = t >> 6, wm = wid >> 2, wn = wid & 3;
  const int sel = (OUTMODE == 0) ? (int)blockIdx.z : 0;
  const u16* Bt;
  const float* bias;
  if constexpr (OUTMODE == 0) {
    Bt = (sel == 0) ? W0 : (sel == 1) ? W1 : W2;
    bias = (sel == 0) ? b0 : (sel == 1) ? b1 : b2;
  } else {
    Bt = W0; bias = b0;
  }
  const int m0 = blockIdx.y * 256, n0 = blockIdx.x * 256;
  // staging: thread t covers LDS rows (i*64 + t>>3), 16B col (t&7)*16 of a [128][128B] half-tile
  const int srow = t >> 3;
  const int pb = (t & 7) * 16;
  const int sswz = (srow & 7) << 4;  // source pre-swizzle (both-sides XOR, rule #21)

  // stage one half-tile (128 rows x 64 bf16) into buf: ab=0 A, ab=1 B; half = row-half
  auto STAGE = [&](int buf, int ab, int half, int kt) {
    const u16* src = ab ? Bt : A;
    const int br = (ab ? n0 : m0) + half * 128;
#pragma unroll
    for (int i = 0; i < 2; ++i) {
      int rl = i * 64 + srow;
      gl_lds16((const char*)src + ((size_t)(br + rl) * K + kt * 64) * 2 + (pb ^ sswz),
               lds + buf * 65536 + ab * 32768 + half * 16384 + i * 8192 + t * 16);
    }
  };
  // fragment reads (swizzled): row&7 == lr&7 (tile bases are multiples of 16)
  auto LDA = [&](int buf, int m, int kk) -> bf16x8 {
    int row = wm * 128 + m * 16 + lr;
    return *(const bf16x8*)(lds + buf * 65536 + row * 128 + ((kk * 64 + lg * 16) ^ ((lr & 7) << 4)));
  };
  auto LDB = [&](int buf, int n, int kk) -> bf16x8 {
    int row = wn * 64 + n * 16 + lr;
    return *(const bf16x8*)(lds + buf * 65536 + 32768 + row * 128 + ((kk * 64 + lg * 16) ^ ((lr & 7) << 4)));
  };

  f32x4 acc[8][4] = {};
  bf16x8 af[8][2], bfr[4][2];

  auto QUAD = [&](int mh, int nh) {
    __builtin_amdgcn_s_setprio(1);
#pragma unroll
    for (int m = 0; m < 4; ++m)
#pragma unroll
      for (int n = 0; n < 2; ++n)
#pragma unroll
        for (int kk = 0; kk < 2; ++kk)
          acc[mh * 4 + m][nh * 2 + n] =
              mfma16(af[mh * 4 + m][kk], bfr[nh * 2 + n][kk], acc[mh * 4 + m][nh * 2 + n]);
    __builtin_amdgcn_s_setprio(0);
  };

  // prologue: tile0 all 4 halves + tile1 A0,A1,B0  (7 stages); drain to 3-in-flight
  STAGE(0, 0, 0, 0); STAGE(0, 0, 1, 0); STAGE(0, 1, 0, 0); STAGE(0, 1, 1, 0);
  STAGE(1, 0, 0, 1); STAGE(1, 0, 1, 1); STAGE(1, 1, 0, 1);
  asm volatile("s_waitcnt vmcnt(6)" ::: "memory");
  bar();

  for (int j = 0; j < NK; ++j) {
    const int c = j & 1;
    // ---- P1: quadrant (mh0,nh0); reads A m0-3 + B n0-1 (12); stage B1 of j+1
#pragma unroll
    for (int m = 0; m < 4; ++m) { af[m][0] = LDA(c, m, 0); af[m][1] = LDA(c, m, 1); }
#pragma unroll
    for (int n = 0; n < 2; ++n) { bfr[n][0] = LDB(c, n, 0); bfr[n][1] = LDB(c, n, 1); }
    if (j + 1 < NK) STAGE(c ^ 1, 1, 1, j + 1);
    bar();
    QUAD(0, 0);
    bar();
    // ---- P2: quadrant (mh1,nh0); reads A m4-7 (8)
#pragma unroll
    for (int m = 0; m < 4; ++m) { af[4 + m][0] = LDA(c, 4 + m, 0); af[4 + m][1] = LDA(c, 4 + m, 1); }
    bar();
    QUAD(1, 0);
    bar();
    // ---- P3: quadrant (mh1,nh1); reads B n2-3 (4); stage A0 of j+2 (A reads done at P2)
#pragma unroll
    for (int n = 0; n < 2; ++n) { bfr[2 + n][0] = LDB(c, 2 + n, 0); bfr[2 + n][1] = LDB(c, 2 + n, 1); }
    if (j + 2 < NK) STAGE(c, 0, 0, j + 2);
    bar();
    QUAD(1, 1);
    bar();
    // ---- P4: quadrant (mh0,nh1); stage A1,B0 of j+2; counted vmcnt -> tile j+1 complete
    if (j + 2 < NK) { STAGE(c, 0, 1, j + 2); STAGE(c, 1, 0, j + 2); }
    if (j < NK - 2) asm volatile("s_waitcnt vmcnt(6)" ::: "memory");
    else            asm volatile("s_waitcnt vmcnt(0)" ::: "memory");
    bar();
    QUAD(0, 1);
    bar();
  }

  // epilogue: bias + store
#pragma unroll
  for (int n = 0; n < 4; ++n) {
    int col = n0 + wn * 64 + n * 16 + lr;
    float bv = bias[col];
#pragma unroll
    for (int m = 0; m < 8; ++m) {
      int row0 = m0 + wm * 128 + m * 16 + lg * 4;
      f32x4 v = acc[m][n];
#pragma unroll
      for (int r = 0; r < 4; ++r) {
        float val = v[r] + bv;
        if constexpr (OUTMODE == 0) {
          if (sel == 2) {
            int gm = row0 + r;
            int b = gm >> 11, tt2 = gm & 2047;
            int h = col >> 7, d = col & 127;
            O2[(((size_t)(b * HH + h) * 128 + d) << 11) + tt2] = to_bf16u(val);
          } else {
            ((sel == 0) ? O0 : O1)[(size_t)(row0 + r) * 2048 + col] = to_bf16u(val);
          }
        } else {
          OF[(size_t)(row0 + r) * 2048 + col] = val;
        }
      }
    }
  }
}

// ---------------- flash attention v3: pair-balanced 64-row subtile blocks ----------------
__global__ __launch_bounds__(256) void k_attn(const u16* __restrict__ Q, const u16* __restrict__ Kx,
                                              const u16* __restrict__ Vt, u16* __restrict__ O,
                                              const float* __restrict__ slopes) {
  __shared__ __align__(16) char KL[2][16384];  // K tile [64][128] bf16, swizzled rows (256B)
  __shared__ __align__(16) char VL[2][16384];  // Vt tile [128][64] bf16, swizzled rows (128B)
  __shared__ __align__(16) char PL[8192];      // P per wave [16][64] bf16, swizzled rows (128B)
  const int t = threadIdx.x, wid = t >> 6, lane = t & 63, lg = lane >> 4, lr = lane & 15;
  const int p = blockIdx.x >> 1, sub = blockIdx.x & 1;
  const int bh = blockIdx.y, b = bh >> 4, h = bh & 15;
  const float slope2 = slopes[h] * 1.4426950408889634f;
  const float scale2 = 0.088388347648318447f * 1.4426950408889634f;  // log2e / sqrt(128)

  const int krow_ = t >> 4, kcolb = (t & 15) * 16;
  const int vrow_ = t >> 3, vcolb = (t & 7) * 16;

  auto STAGE = [&](int buf, int kv0) {
#pragma unroll
    for (int i = 0; i < 4; ++i) {
      int row = i * 16 + krow_;
      int scol = kcolb ^ ((row & 7) << 4);
      gl_lds16((const char*)Kx + ((size_t)(b * TT + kv0 + row) * DD + h * 128) * 2 + scol,
               KL[buf] + i * 4096 + wid * 1024);
      int vrow = i * 32 + vrow_;
      int svcol = vcolb ^ ((vrow & 7) << 4);
      gl_lds16((const char*)Vt + ((size_t)(bh * 128 + vrow) * TT + kv0) * 2 + svcol,
               VL[buf] + i * 4096 + wid * 1024);
    }
  };

  f32x4 cjb;
#pragma unroll
  for (int kb = 0; kb < 4; ++kb) cjb[kb] = slope2 * (float)(kb * 16 + lr);

  int cur = 0;
  STAGE(0, 0);
  __syncthreads();

#pragma unroll 1
  for (int e = 0; e < 2; ++e) {
    const int qt = e ? (15 - p) : p;
    const int r0 = qt * 128 + sub * 64;
    const int wq0 = r0 + wid * 16;
    const int nt = r0 / 64 + 1;

    bf16x8 qf[4];
#pragma unroll
    for (int ds = 0; ds < 4; ++ds)
      qf[ds] = *(const bf16x8*)(Q + (size_t)(b * TT + wq0 + lr) * DD + h * 128 + ds * 32 + lg * 8);

    f32x4 of[8] = {};
    f32x4 mx, ls;
#pragma unroll
    for (int r = 0; r < 4; ++r) { mx[r] = -3e38f; ls[r] = 0.f; }
    f32x4 ri;
#pragma unroll
    for (int r = 0; r < 4; ++r) ri[r] = slope2 * (float)(wq0 + lg * 4 + r);

#pragma unroll 1
    for (int kt = 0; kt < nt; ++kt) {
      const int kv0 = kt * 64;
      const bool more = (kt + 1 < nt) || (e == 0);
      const int nxt = (kt + 1 < nt) ? (kt + 1) * 64 : 0;
      if (more) STAGE(cur ^ 1, nxt);

      if (kv0 <= wq0 + 15) {
        const char* kl = KL[cur];
        const char* vl = VL[cur];
        f32x4 s[4] = {};
#pragma unroll
        for (int ds = 0; ds < 4; ++ds)
#pragma unroll
          for (int kb = 0; kb < 4; ++kb) {
            int row = kb * 16 + lr;
            bf16x8 kf = *(const bf16x8*)(kl + row * 256 + ((ds * 64 + lg * 16) ^ ((row & 7) << 4)));
            s[kb] = mfma16(qf[ds], kf, s[kb]);
          }
        const float ct = slope2 * (float)kv0;
        const bool diag = (kv0 + 63 > wq0);
        f32x4 rm;
#pragma unroll
        for (int r = 0; r < 4; ++r) rm[r] = -3e38f;
#pragma unroll
        for (int kb = 0; kb < 4; ++kb) {
          float cj = cjb[kb] + ct;
#pragma unroll
          for (int r = 0; r < 4; ++r) {
            float v = fmaf(s[kb][r], scale2, cj - ri[r]);
            if (diag) {
              int j = kv0 + kb * 16 + lr, i = wq0 + lg * 4 + r;
              v = (j > i) ? -3e38f : v;
            }
            s[kb][r] = v;
            rm[r] = fmaxf(rm[r], v);
          }
        }
#pragma unroll
        for (int off = 1; off < 16; off <<= 1)
#pragma unroll
          for (int r = 0; r < 4; ++r) rm[r] = fmaxf(rm[r], __shfl_xor(rm[r], off));
        bool need = false;
#pragma unroll
        for (int r = 0; r < 4; ++r) need = need || (rm[r] > mx[r] + 8.f);
        if (__any(need)) {
          f32x4 sc;
#pragma unroll
          for (int r = 0; r < 4; ++r) {
            float mn = fmaxf(mx[r], rm[r]);
            sc[r] = exp2f(mx[r] - mn);
            mx[r] = mn;
            ls[r] *= sc[r];
          }
#pragma unroll
          for (int db = 0; db < 8; ++db)
#pragma unroll
            for (int r = 0; r < 4; ++r) of[db][r] *= sc[r];
        }
        f32x4 rs = {};
#pragma unroll
        for (int kb = 0; kb < 4; ++kb)
#pragma unroll
          for (int r = 0; r < 4; ++r) {
            float pv = exp2f(s[kb][r] - mx[r]);
            s[kb][r] = pv;
            rs[r] += pv;
          }
#pragma unroll
        for (int off = 1; off < 16; off <<= 1)
#pragma unroll
          for (int r = 0; r < 4; ++r) rs[r] += __shfl_xor(rs[r], off);
#pragma unroll
        for (int r = 0; r < 4; ++r) ls[r] += rs[r];
        char* pw = PL + wid * 2048;
#pragma unroll
        for (int kb = 0; kb < 4; ++kb) {
          int colb = (kb * 16 + lr) * 2;
#pragma unroll
          for (int r = 0; r < 4; ++r) {
            int row = lg * 4 + r;
            *(u16*)(pw + row * 128 + (colb ^ ((row & 7) << 4))) = to_bf16u(s[kb][r]);
          }
        }
        const char* prd = PL + wid * 2048;
#pragma unroll
        for (int ks = 0; ks < 2; ++ks) {
          bf16x8 pf = *(const bf16x8*)(prd + lr * 128 + ((ks * 64 + lg * 16) ^ ((lr & 7) << 4)));
#pragma unroll
          for (int db = 0; db < 8; ++db) {
            int vrow = db * 16 + lr;
            bf16x8 vf = *(const bf16x8*)(vl + vrow * 128 + ((ks * 64 + lg * 16) ^ ((vrow & 7) << 4)));
            of[db] = mfma16(pf, vf, of[db]);
          }
        }
      }
      __syncthreads();
      cur ^= 1;
    }
    f32x4 inv;
#pragma unroll
    for (int r = 0; r < 4; ++r) inv[r] = 1.0f / ls[r];
#pragma unroll
    for (int db = 0; db < 8; ++db)
#pragma unroll
      for (int r = 0; r < 4; ++r) {
        int row = wq0 + lg * 4 + r;
        O[(size_t)(b * TT + row) * DD + h * 128 + db * 16 + lr] = to_bf16u(of[db][r] * inv[r]);
      }
  }
}

extern "C" void kernel_launch(void* const* d_in, const int* in_sizes, int n_in,
                              void* d_out, int out_size, void* d_ws, size_t ws_size,
                              hipStream_t stream) {
  const float* x  = (const float*)d_in[0];
  // d_in[1] is the causal mask -- always tril, hardcoded in k_attn
  const float* wq = (const float*)d_in[2];
  const float* bq = (const float*)d_in[3];
  const float* wk = (const float*)d_in[4];
  const float* bk = (const float*)d_in[5];
  const float* wv = (const float*)d_in[6];
  const float* bv = (const float*)d_in[7];
  const float* wo = (const float*)d_in[8];
  const float* bo = (const float*)d_in[9];
  const float* sl = (const float*)d_in[10];

  char* ws = (char*)d_ws;
  u16* xb  = (u16*)(ws);                      // 16 MiB (B*T,D) bf16; reused as O after attn
  u16* wqt = (u16*)(ws + 16777216);           // 8 MiB each, (N,K) bf16
  u16* wkt = (u16*)(ws + 25165824);
  u16* wvt = (u16*)(ws + 33554432);
  u16* wot = (u16*)(ws + 41943040);
  u16* Qb  = (u16*)(ws + 50331648);           // 16 MiB
  u16* Kb  = (u16*)(ws + 67108864);           // 16 MiB
  u16* Vtb = (u16*)(ws + 83886080);           // 16 MiB (B,H,128,T)
  u16* Ob  = xb;

  hipFuncSetAttribute((const void*)&k_gemm256<0>, hipFuncAttributeMaxDynamicSharedMemorySize, 131072);
  hipFuncSetAttribute((const void*)&k_gemm256<1>, hipFuncAttributeMaxDynamicSharedMemorySize, 131072);

  const int n_x = BB * TT * DD;
  hipLaunchKernelGGL(k_cvt, dim3(4096), dim3(256), 0, stream, x, xb, n_x);
  hipLaunchKernelGGL(k_wtrans, dim3(64, 64, 4), dim3(256), 0, stream,
                     wq, wk, wv, wo, wqt, wkt, wvt, wot);
  hipLaunchKernelGGL((k_gemm256<0>), dim3(8, 16, 3), dim3(512), 131072, stream,
                     xb, wqt, wkt, wvt, bq, bk, bv, Qb, Kb, Vtb, (float*)nullptr);
  hipLaunchKernelGGL(k_attn, dim3(16, 32), dim3(256), 0, stream, Qb, Kb, Vtb, Ob, sl);
  hipLaunchKernelGGL((k_gemm256<1>), dim3(8, 16, 1), dim3(512), 131072, stream,
                     Ob, wot, nullptr, nullptr, bo, nullptr, nullptr,
                     nullptr, nullptr, nullptr, (float*)d_out);
}

// Round 7
// 435.347 us; speedup vs baseline: 1.1237x; 1.1237x over previous
//
#include <hip/hip_runtime.h>

typedef unsigned short u16;
typedef float f32x4 __attribute__((ext_vector_type(4)));
typedef __bf16 bf16x8 __attribute__((ext_vector_type(8)));

#define DEV static __device__ __forceinline__

constexpr int BB = 2, TT = 2048, DD = 2048, HH = 16;

DEV u16 to_bf16u(float f) { return __builtin_bit_cast(u16, (__bf16)f); }

DEV void gl_lds16(const void* g, void* l) {
  __builtin_amdgcn_global_load_lds((const __attribute__((address_space(1))) void*)g,
                                   (__attribute__((address_space(3))) void*)l, 16, 0, 0);
}

DEV f32x4 mfma16(bf16x8 a, bf16x8 b, f32x4 c) {
  return __builtin_amdgcn_mfma_f32_16x16x32_bf16(a, b, c, 0, 0, 0);
}

// ---------------- fp32 -> bf16 convert (8 elems/thread) ----------------
__global__ __launch_bounds__(256) void k_cvt(const float* __restrict__ in,
                                             u16* __restrict__ out, int n) {
  int i = (blockIdx.x * 256 + threadIdx.x) * 8;
  if (i >= n) return;
  float4 a = *(const float4*)(in + i);
  float4 b = *(const float4*)(in + i + 4);
  ushort4 u0, u1;
  u0.x = to_bf16u(a.x); u0.y = to_bf16u(a.y); u0.z = to_bf16u(a.z); u0.w = to_bf16u(a.w);
  u1.x = to_bf16u(b.x); u1.y = to_bf16u(b.y); u1.z = to_bf16u(b.z); u1.w = to_bf16u(b.w);
  *(ushort4*)(out + i) = u0;
  *(ushort4*)(out + i + 4) = u1;
}

// ---------------- weight transpose + convert: w (K,N) -> wt (N,K) bf16 ----------------
__global__ __launch_bounds__(256) void k_wtrans(const float* __restrict__ w0, const float* __restrict__ w1,
                                                const float* __restrict__ w2, const float* __restrict__ w3,
                                                u16* __restrict__ o0, u16* __restrict__ o1,
                                                u16* __restrict__ o2, u16* __restrict__ o3) {
  __shared__ float tile[32][33];
  const float* w; u16* o;
  switch (blockIdx.z) {
    case 0: w = w0; o = o0; break;
    case 1: w = w1; o = o1; break;
    case 2: w = w2; o = o2; break;
    default: w = w3; o = o3; break;
  }
  int bx = blockIdx.x * 32;  // n
  int by = blockIdx.y * 32;  // k
  int tx = threadIdx.x & 31, ty = threadIdx.x >> 5;
#pragma unroll
  for (int j = ty; j < 32; j += 8)
    tile[j][tx] = w[(size_t)(by + j) * DD + bx + tx];
  __syncthreads();
#pragma unroll
  for (int j = ty; j < 32; j += 8)
    o[(size_t)(bx + j) * DD + by + tx] = to_bf16u(tile[tx][j]);
}

// ---------------- 128^2 GEMM, BK=64: C(M,2048) = A(M,2048)*Bt(2048,2048)^T + bias ----------------
// MODE 0: QKV fused via blockIdx.z (sel2 -> V transposed (B,H,128,T)); MODE 1: f32 out.
template <int MODE>
__global__ __launch_bounds__(256, 4) void k_gemm(const u16* __restrict__ A,
                                                 const u16* __restrict__ W0, const u16* __restrict__ W1,
                                                 const u16* __restrict__ W2,
                                                 const float* __restrict__ b0, const float* __restrict__ b1,
                                                 const float* __restrict__ b2,
                                                 u16* __restrict__ O0, u16* __restrict__ O1,
                                                 u16* __restrict__ O2, float* __restrict__ OF) {
  constexpr int K = 2048, N = 2048;
  __shared__ __align__(16) u16 As[128 * 64], Bs[128 * 64];  // 16 KB each, rows 128B
  const int sel = (MODE == 0) ? (int)blockIdx.z : 0;
  const u16* Bt; const float* bias;
  if constexpr (MODE == 0) {
    Bt = (sel == 0) ? W0 : (sel == 1) ? W1 : W2;
    bias = (sel == 0) ? b0 : (sel == 1) ? b1 : b2;
  } else { Bt = W0; bias = b0; }
  const int t = threadIdx.x;
  const int wid = t >> 6, lane = t & 63, lg = lane >> 4, lr = lane & 15;
  const int m0 = blockIdx.y * 128, n0 = blockIdx.x * 128;
  const int wr = (wid >> 1) * 64, wc = (wid & 1) * 64;
  f32x4 acc[4][4] = {};
  // staging: pass i covers rows i*32 + (t>>3), chunk (t&7)*16 of a [128][128B] tile
  const int srow = t >> 3;
  const int sc = (t & 7) * 16;
  const int sswz = (srow & 7) << 4;  // both-sides XOR swizzle (rule #21)

  for (int k0 = 0; k0 < K; k0 += 64) {
#pragma unroll
    for (int i = 0; i < 4; ++i) {
      int row = i * 32 + srow;
      gl_lds16((const char*)A + ((size_t)(m0 + row) * K + k0) * 2 + (sc ^ sswz),
               (char*)As + i * 4096 + t * 16);
      gl_lds16((const char*)Bt + ((size_t)(n0 + row) * K + k0) * 2 + (sc ^ sswz),
               (char*)Bs + i * 4096 + t * 16);
    }
    __syncthreads();
    bf16x8 af[4][2], bfr[4][2];
#pragma unroll
    for (int m = 0; m < 4; ++m) {
      int row = wr + m * 16 + lr;
#pragma unroll
      for (int kk = 0; kk < 2; ++kk)
        af[m][kk] = *(const bf16x8*)((const char*)As + row * 128 + ((kk * 64 + lg * 16) ^ ((row & 7) << 4)));
    }
#pragma unroll
    for (int n = 0; n < 4; ++n) {
      int row = wc + n * 16 + lr;
#pragma unroll
      for (int kk = 0; kk < 2; ++kk)
        bfr[n][kk] = *(const bf16x8*)((const char*)Bs + row * 128 + ((kk * 64 + lg * 16) ^ ((row & 7) << 4)));
    }
#pragma unroll
    for (int m = 0; m < 4; ++m)
#pragma unroll
      for (int n = 0; n < 4; ++n)
#pragma unroll
        for (int kk = 0; kk < 2; ++kk)
          acc[m][n] = mfma16(af[m][kk], bfr[n][kk], acc[m][n]);
    __syncthreads();
  }

#pragma unroll
  for (int n = 0; n < 4; ++n) {
    int col = n0 + wc + n * 16 + lr;
    float bv = bias[col];
#pragma unroll
    for (int m = 0; m < 4; ++m) {
      int row = m0 + wr + m * 16 + lg * 4;
      f32x4 v = acc[m][n];
#pragma unroll
      for (int r = 0; r < 4; ++r) {
        float val = v[r] + bv;
        if constexpr (MODE == 0) {
          if (sel == 2) {
            int gm = row + r;
            int b = gm >> 11, tt2 = gm & 2047;
            int h = col >> 7, d = col & 127;
            O2[(((size_t)(b * HH + h) * 128 + d) << 11) + tt2] = to_bf16u(val);
          } else {
            ((sel == 0) ? O0 : O1)[(size_t)(row + r) * N + col] = to_bf16u(val);
          }
        } else {
          OF[(size_t)(row + r) * N + col] = val;
        }
      }
    }
  }
}

// ---------------- flash attention v4: 256 blocks x 512 thr, 8 waves x 16 q-rows ----------------
// block p (0..7) x bh: processes q-tile p, then q-tile 15-p (128 rows each).
// Work/block = 34 kv-tiles uniformly; exactly 1 block/CU.
__global__ __launch_bounds__(512) void k_attn(const u16* __restrict__ Q, const u16* __restrict__ Kx,
                                              const u16* __restrict__ Vt, u16* __restrict__ O,
                                              const float* __restrict__ slopes) {
  __shared__ __align__(16) char KL[2][16384];  // K tile [64][256B] swizzled
  __shared__ __align__(16) char VL[2][16384];  // Vt tile [128][128B] swizzled
  __shared__ __align__(16) char PL[16384];     // P per wave [16][128B] swizzled
  const int t = threadIdx.x, wid = t >> 6, lane = t & 63, lg = lane >> 4, lr = lane & 15;
  const int p = blockIdx.x;
  const int bh = blockIdx.y, b = bh >> 4, h = bh & 15;
  const float slope2 = slopes[h] * 1.4426950408889634f;
  const float scale2 = 0.088388347648318447f * 1.4426950408889634f;  // log2e / sqrt(128)

  // staging (512 threads): K pass P: row P*32 + (t>>4), chunk (t&15)*16; V pass P: row P*64 + (t>>3), chunk (t&7)*16
  const int krow_ = t >> 4, kc_ = (t & 15) * 16;
  const int vrow_ = t >> 3, vc_ = (t & 7) * 16;

  auto STAGE = [&](int buf, int kv0) {
#pragma unroll
    for (int i = 0; i < 2; ++i) {
      int row = i * 32 + krow_;
      gl_lds16((const char*)Kx + ((size_t)(b * TT + kv0 + row) * DD + h * 128) * 2 + (kc_ ^ ((row & 7) << 4)),
               KL[buf] + i * 8192 + t * 16);
      int vrow = i * 64 + vrow_;
      gl_lds16((const char*)Vt + ((size_t)(bh * 128 + vrow) * TT + kv0) * 2 + (vc_ ^ ((vrow & 7) << 4)),
               VL[buf] + i * 8192 + t * 16);
    }
  };

  f32x4 cjb;
#pragma unroll
  for (int kb = 0; kb < 4; ++kb) cjb[kb] = slope2 * (float)(kb * 16 + lr);

  int cur = 0;
  STAGE(0, 0);
  __syncthreads();

#pragma unroll 1
  for (int e = 0; e < 2; ++e) {
    const int qt = e ? (15 - p) : p;
    const int r0 = qt * 128;
    const int wq0 = r0 + wid * 16;          // wave's 16 q-rows
    const int nt = 2 * qt + 2;              // kv tiles needed

    bf16x8 qf[4];
#pragma unroll
    for (int ds = 0; ds < 4; ++ds)
      qf[ds] = *(const bf16x8*)(Q + (size_t)(b * TT + wq0 + lr) * DD + h * 128 + ds * 32 + lg * 8);

    f32x4 of[8] = {};
    f32x4 mx, ls;
#pragma unroll
    for (int r = 0; r < 4; ++r) { mx[r] = -3e38f; ls[r] = 0.f; }
    f32x4 ri;
#pragma unroll
    for (int r = 0; r < 4; ++r) ri[r] = slope2 * (float)(wq0 + lg * 4 + r);

#pragma unroll 1
    for (int kt = 0; kt < nt; ++kt) {
      const int kv0 = kt * 64;
      const bool more = (kt + 1 < nt) || (e == 0);
      const int nxt = (kt + 1 < nt) ? (kt + 1) * 64 : 0;
      if (more) STAGE(cur ^ 1, nxt);

      if (kv0 <= wq0 + 15) {  // wave has unmasked cols in this tile
        const char* kl = KL[cur];
        const char* vl = VL[cur];
        f32x4 s[4] = {};
#pragma unroll
        for (int ds = 0; ds < 4; ++ds)
#pragma unroll
          for (int kb = 0; kb < 4; ++kb) {
            int row = kb * 16 + lr;
            bf16x8 kf = *(const bf16x8*)(kl + row * 256 + ((ds * 64 + lg * 16) ^ ((row & 7) << 4)));
            s[kb] = mfma16(qf[ds], kf, s[kb]);
          }
        const float ct = slope2 * (float)kv0;
        const bool diag = (kv0 + 63 > wq0);
        f32x4 rm;
#pragma unroll
        for (int r = 0; r < 4; ++r) rm[r] = -3e38f;
#pragma unroll
        for (int kb = 0; kb < 4; ++kb) {
          float cj = cjb[kb] + ct;
#pragma unroll
          for (int r = 0; r < 4; ++r) {
            float v = fmaf(s[kb][r], scale2, cj - ri[r]);
            if (diag) {
              int j = kv0 + kb * 16 + lr, i = wq0 + lg * 4 + r;
              v = (j > i) ? -3e38f : v;
            }
            s[kb][r] = v;
            rm[r] = fmaxf(rm[r], v);
          }
        }
#pragma unroll
        for (int off = 1; off < 16; off <<= 1)
#pragma unroll
          for (int r = 0; r < 4; ++r) rm[r] = fmaxf(rm[r], __shfl_xor(rm[r], off));
        bool need = false;
#pragma unroll
        for (int r = 0; r < 4; ++r) need = need || (rm[r] > mx[r] + 8.f);
        if (__any(need)) {
          f32x4 sc;
#pragma unroll
          for (int r = 0; r < 4; ++r) {
            float mn = fmaxf(mx[r], rm[r]);
            sc[r] = exp2f(mx[r] - mn);
            mx[r] = mn;
            ls[r] *= sc[r];
          }
#pragma unroll
          for (int db = 0; db < 8; ++db)
#pragma unroll
            for (int r = 0; r < 4; ++r) of[db][r] *= sc[r];
        }
        f32x4 rs = {};
#pragma unroll
        for (int kb = 0; kb < 4; ++kb)
#pragma unroll
          for (int r = 0; r < 4; ++r) {
            float pv = exp2f(s[kb][r] - mx[r]);
            s[kb][r] = pv;
            rs[r] += pv;
          }
#pragma unroll
        for (int off = 1; off < 16; off <<= 1)
#pragma unroll
          for (int r = 0; r < 4; ++r) rs[r] += __shfl_xor(rs[r], off);
#pragma unroll
        for (int r = 0; r < 4; ++r) ls[r] += rs[r];
        char* pw = PL + wid * 2048;
#pragma unroll
        for (int kb = 0; kb < 4; ++kb) {
          int colb = (kb * 16 + lr) * 2;
#pragma unroll
          for (int r = 0; r < 4; ++r) {
            int row = lg * 4 + r;
            *(u16*)(pw + row * 128 + (colb ^ ((row & 7) << 4))) = to_bf16u(s[kb][r]);
          }
        }
        const char* prd = PL + wid * 2048;
#pragma unroll
        for (int ks = 0; ks < 2; ++ks) {
          bf16x8 pf = *(const bf16x8*)(prd + lr * 128 + ((ks * 64 + lg * 16) ^ ((lr & 7) << 4)));
#pragma unroll
          for (int db = 0; db < 8; ++db) {
            int vrow = db * 16 + lr;
            bf16x8 vf = *(const bf16x8*)(vl + vrow * 128 + ((ks * 64 + lg * 16) ^ ((vrow & 7) << 4)));
            of[db] = mfma16(pf, vf, of[db]);
          }
        }
      }
      __syncthreads();
      cur ^= 1;
    }
    f32x4 inv;
#pragma unroll
    for (int r = 0; r < 4; ++r) inv[r] = 1.0f / ls[r];
#pragma unroll
    for (int db = 0; db < 8; ++db)
#pragma unroll
      for (int r = 0; r < 4; ++r) {
        int row = wq0 + lg * 4 + r;
        O[(size_t)(b * TT + row) * DD + h * 128 + db * 16 + lr] = to_bf16u(of[db][r] * inv[r]);
      }
  }
}

extern "C" void kernel_launch(void* const* d_in, const int* in_sizes, int n_in,
                              void* d_out, int out_size, void* d_ws, size_t ws_size,
                              hipStream_t stream) {
  const float* x  = (const float*)d_in[0];
  // d_in[1] is the causal mask -- always tril, hardcoded in k_attn
  const float* wq = (const float*)d_in[2];
  const float* bq = (const float*)d_in[3];
  const float* wk = (const float*)d_in[4];
  const float* bk = (const float*)d_in[5];
  const float* wv = (const float*)d_in[6];
  const float* bv = (const float*)d_in[7];
  const float* wo = (const float*)d_in[8];
  const float* bo = (const float*)d_in[9];
  const float* sl = (const float*)d_in[10];

  char* ws = (char*)d_ws;
  u16* xb  = (u16*)(ws);                      // 16 MiB (B*T,D) bf16; reused as O after attn
  u16* wqt = (u16*)(ws + 16777216);           // 8 MiB each, (N,K) bf16
  u16* wkt = (u16*)(ws + 25165824);
  u16* wvt = (u16*)(ws + 33554432);
  u16* wot = (u16*)(ws + 41943040);
  u16* Qb  = (u16*)(ws + 50331648);           // 16 MiB
  u16* Kb  = (u16*)(ws + 67108864);           // 16 MiB
  u16* Vtb = (u16*)(ws + 83886080);           // 16 MiB (B,H,128,T)
  u16* Ob  = xb;

  const int n_x = BB * TT * DD;
  hipLaunchKernelGGL(k_cvt, dim3(4096), dim3(256), 0, stream, x, xb, n_x);
  hipLaunchKernelGGL(k_wtrans, dim3(64, 64, 4), dim3(256), 0, stream,
                     wq, wk, wv, wo, wqt, wkt, wvt, wot);
  hipLaunchKernelGGL((k_gemm<0>), dim3(16, 32, 3), dim3(256), 0, stream,
                     xb, wqt, wkt, wvt, bq, bk, bv, Qb, Kb, Vtb, (float*)nullptr);
  hipLaunchKernelGGL(k_attn, dim3(8, 32), dim3(512), 0, stream, Qb, Kb, Vtb, Ob, sl);
  hipLaunchKernelGGL((k_gemm<1>), dim3(16, 32, 1), dim3(256), 0, stream,
                     Ob, wot, nullptr, nullptr, bo, nullptr, nullptr,
                     nullptr, nullptr, nullptr, (float*)d_out);
}